// Round 1
// 482.735 us; speedup vs baseline: 1.0194x; 1.0194x over previous
//
#include <hip/hip_runtime.h>

#define HD   2048
#define HHW  (HD*HD)
#define TX   64          // output tile cols
#define TY   32          // output tile rows
#define S    72          // LDS row stride (floats); 16B-aligned rows, float4-friendly
#define XR   36          // x-tile rows  (TY+4), origin (gi0-2, gj0-4)
#define YR   34          // y-tile rows  (TY+2), origin (gi0-1, gj0-4)

// DT=0.001, DX=0.02 -> DT^2/DX^2 = 0.0025, DT/DX = 0.05

union V4 { float4 v; float f[4]; };

__global__ __launch_bounds__(256, 4) void fused_kernel(
    const float* __restrict__ batch,
    const float* __restrict__ rs,
    const float* __restrict__ x_tt_in,
    const float* __restrict__ x_t_in,
    const float* __restrict__ conv_v,
    const float* __restrict__ conv_g,
    const float* __restrict__ conv_b,
    const int* __restrict__ p_bsize,
    const int* __restrict__ p_flag,
    const int* __restrict__ p_flagnum,
    float* __restrict__ out)
{
    // 3 input tiles (single-touch global reads) + conv output tile
    __shared__ float sT[XR * S];   // xtt tile
    __shared__ float sX[XR * S];   // xt  tile
    __shared__ float sR[XR * S];   // rs  tile
    __shared__ float sY[YR * S];   // y (conv) tile
    // total LDS = (3*36 + 34)*72*4 = 40896 B -> 4 blocks/CU

    const int tid = threadIdx.x;
    const int gi0 = blockIdx.y * TY;
    const int gj0 = blockIdx.x * TX;

    const int base = ((p_flag[0] - 1) * p_bsize[0] + (p_flagnum[0] - 1)) * HHW;
    const float* __restrict__ xtt = batch + base;
    const float* __restrict__ xt  = batch + base + HHW;

    // ---- weights (uniform address -> scalar loads), normalize once ----
    float w[27];
    float ss = 0.f;
    #pragma unroll
    for (int k = 0; k < 27; ++k) { w[k] = conv_v[k]; ss += w[k] * w[k]; }
    const float scale = conv_g[0] / sqrtf(ss);
    const float bias  = conv_b[0];

    // ---- stage 0: xtt/xt/rs halo tiles -> LDS via aligned float4 ----
    // chunk gj = gj0-4+4*cc is 16B-aligned; HD%4==0 => chunks fully in or out
#define STAGE(DST, SRC)                                                     \
    for (int i = tid; i < XR * 18; i += 256) {                              \
        const int r  = i / 18;                                              \
        const int cc = i - r * 18;                                          \
        const int gi = gi0 - 2 + r;                                         \
        const int gj = gj0 - 4 + (cc << 2);                                 \
        float4 val = make_float4(0.f, 0.f, 0.f, 0.f);                       \
        if ((unsigned)gi < (unsigned)HD && (unsigned)gj <= (unsigned)(HD-4))\
            val = *(const float4*)(SRC + gi * HD + gj);                     \
        *(float4*)&DST[r * S + (cc << 2)] = val;                            \
    }

    STAGE(sT, xtt)
    STAGE(sX, xt)
    STAGE(sR, rs)
#undef STAGE
    __syncthreads();

    // ---- stage 1: y = conv3x3([xtt, xt, rs]) from LDS only ----
    // vector region: 34 rows x 16 col-groups (cols lj=4..67 == gj0..gj0+63)
#define ACC9(SB, WB) {                                                      \
        V4 a, b, c;                                                         \
        a.v = *(const float4*)&SB[o - 4];                                   \
        b.v = *(const float4*)&SB[o];                                       \
        c.v = *(const float4*)&SB[o + 4];                                   \
        const float w0 = w[WB], w1 = w[WB + 1], w2 = w[WB + 2];             \
        ax += w0 * a.f[3] + w1 * b.f[0] + w2 * b.f[1];                      \
        ay += w0 * b.f[0] + w1 * b.f[1] + w2 * b.f[2];                      \
        az += w0 * b.f[1] + w1 * b.f[2] + w2 * b.f[3];                      \
        aw += w0 * b.f[2] + w1 * b.f[3] + w2 * c.f[0];                      \
    }

    for (int t = tid; t < 34 * 16; t += 256) {
        const int row = t >> 4;                 // y-tile row (gi = gi0-1+row)
        const int ljc = ((t & 15) << 2) + 4;    // tile col of first output
        float ax = 0.f, ay = 0.f, az = 0.f, aw = 0.f;
        #pragma unroll
        for (int kh = 0; kh < 3; ++kh) {
            const int o = (row + kh) * S + ljc;
            ACC9(sT, kh * 3)
            ACC9(sX, 9 + kh * 3)
            ACC9(sR, 18 + kh * 3)
        }
        V4 r4;
        r4.f[0] = bias + scale * ax;
        r4.f[1] = bias + scale * ay;
        r4.f[2] = bias + scale * az;
        r4.f[3] = bias + scale * aw;
        *(float4*)&sY[row * S + ljc] = r4.v;
    }
#undef ACC9

    // edge columns lj=3 (gj0-1) and lj=68 (gj0+64): 34 rows x 2, scalar
    if (tid < 68) {
        const int row = tid >> 1;
        const int lj  = (tid & 1) ? 68 : 3;
        float acc = 0.f;
        #pragma unroll
        for (int kh = 0; kh < 3; ++kh) {
            const int o = (row + kh) * S + lj;
            acc += w[kh*3+0]      * sT[o-1] + w[kh*3+1]      * sT[o] + w[kh*3+2]      * sT[o+1];
            acc += w[9+kh*3+0]    * sX[o-1] + w[9+kh*3+1]    * sX[o] + w[9+kh*3+2]    * sX[o+1];
            acc += w[18+kh*3+0]   * sR[o-1] + w[18+kh*3+1]   * sR[o] + w[18+kh*3+2]   * sR[o+1];
        }
        sY[row * S + lj] = bias + scale * acc;
    }
    __syncthreads();

    // ---- stage 2: all 7 output planes, 4 cols/thread via float4 ----
    const int c4 = (tid & 15) << 2;     // col offset within tile (0..60)
    const int r0 = tid >> 4;            // 16 rows per pass
    #pragma unroll
    for (int pass = 0; pass < 2; ++pass) {
        const int row = r0 + (pass << 4);
        const int gi  = gi0 + row;
        const int gjb = gj0 + c4;
        const int idx = gi * HD + gjb;

        V4 att, at4;
        att.v = *(const float4*)(x_tt_in + idx);
        at4.v = *(const float4*)(x_t_in  + idx);

        const int xb = (row + 2) * S + c4 + 4;
        V4 xc, xu, xd, xl, xr_, xo, rc;
        xc.v  = *(const float4*)&sX[xb];
        xu.v  = *(const float4*)&sX[xb - S];
        xd.v  = *(const float4*)&sX[xb + S];
        xl.v  = *(const float4*)&sX[xb - 4];
        xr_.v = *(const float4*)&sX[xb + 4];
        xo.v  = *(const float4*)&sT[xb];
        rc.v  = *(const float4*)&sR[xb];

        const int yb = (row + 1) * S + c4 + 4;
        V4 yc, yu, yd, yl, yr_;
        yc.v  = *(const float4*)&sY[yb];
        yu.v  = *(const float4*)&sY[yb - S];
        yd.v  = *(const float4*)&sY[yb + S];
        yl.v  = *(const float4*)&sY[yb - 4];
        yr_.v = *(const float4*)&sY[yb + 4];

        const bool gi_int = (gi >= 1) && (gi <= HD - 2);
        V4 o2, o5, o6;
        #pragma unroll
        for (int e = 0; e < 4; ++e) {
            const int gj = gjb + e;
            const float xce  = xc.f[e];
            const float rce  = rc.f[e];
            const float xlft = e        ? xc.f[e-1] : xl.f[3];
            const float xrgt = (e < 3)  ? xc.f[e+1] : xr_.f[0];
            const float ylft = e        ? yc.f[e-1] : yl.f[3];
            const float yrgt = (e < 3)  ? yc.f[e+1] : yr_.f[0];
            const bool interior = gi_int && (gj >= 1) && (gj <= HD - 2);

            const float coef = rce * rce * 0.0025f;
            const float tm   = 2.f * xce - xo.f[e];
            const float lapx = xu.f[e] + xd.f[e] + xlft + xrgt - 4.f * xce;
            const float lapy = yu.f[e] + yd.f[e] + ylft + yrgt - 4.f * yc.f[e];

            float xt4v = 0.f, ypre;
            if (interior) { xt4v = tm + lapx * coef; ypre = tm + lapy * coef; }
            else          { ypre = yc.f[e]; }

            // BC precedence chain (reference overwrite order):
            // row0=0 -> left col -> anti-diagonal -> right col -> rowH-1=0
            float v = ypre;
            if (gi == 0)            v = 0.f;
            if (gj == 0)            v = xce - 0.05f * rce * (xce - xrgt);  // xt[gi][1]
            if (gi_int && gj == HD - gi)
                                    v = sX[(row + 1) * S + c4 + e + 3];    // xt[gi-1][gj-1]
            if (gj == HD - 1)       v = xce - 0.05f * rce * (xce - xlft);  // xt[gi][HD-2]
            if (gi == HD - 1)       v = 0.f;

            o2.f[e] = v; o5.f[e] = ypre; o6.f[e] = xt4v;
        }

        *(float4*)(out + idx)           = att.v;  // plane 0: x_tt
        *(float4*)(out + HHW + idx)     = at4.v;  // plane 1: x_t
        *(float4*)(out + 2 * HHW + idx) = o2.v;   // plane 2: x7
        *(float4*)(out + 3 * HHW + idx) = att.v;  // plane 3: x_tt
        *(float4*)(out + 4 * HHW + idx) = at4.v;  // plane 4: x_t
        *(float4*)(out + 5 * HHW + idx) = o5.v;   // plane 5: x7_pre
        *(float4*)(out + 6 * HHW + idx) = o6.v;   // plane 6: x_t4
    }
}

// ---------------- observation scatter (runs last => wins over BCs) ---------
__global__ __launch_bounds__(256) void scatter_kernel(
    const float* __restrict__ ref_sol,
    const int* __restrict__ loc_x,
    const int* __restrict__ loc_y,
    const int* __restrict__ p_bsize,
    const int* __restrict__ p_id,
    const int* __restrict__ p_flagnum,
    float* __restrict__ out)
{
    int k = blockIdx.x * blockDim.x + threadIdx.x;
    if (k >= 256) return;
    int lx = loc_x[k];
    if (lx == -1) return;
    int ly = loc_y[k];
    int off = (p_id[0] * p_bsize[0] + (p_flagnum[0] - 1) + 2) * HHW;
    out[2 * HHW + lx * HD + ly] = ref_sol[off + lx * HD + ly];
}

extern "C" void kernel_launch(void* const* d_in, const int* in_sizes, int n_in,
                              void* d_out, int out_size, void* d_ws, size_t ws_size,
                              hipStream_t stream) {
    const float* ref_speed = (const float*)d_in[0];
    const float* batch     = (const float*)d_in[1];
    const float* x_tt      = (const float*)d_in[2];
    const float* x_t       = (const float*)d_in[3];
    const float* ref_sol   = (const float*)d_in[4];
    const float* conv_v    = (const float*)d_in[5];
    const float* conv_g    = (const float*)d_in[6];
    const float* conv_b    = (const float*)d_in[7];
    const int*   loc_x     = (const int*)d_in[8];
    const int*   loc_y     = (const int*)d_in[9];
    const int*   bsize     = (const int*)d_in[10];
    const int*   id        = (const int*)d_in[11];
    const int*   flag      = (const int*)d_in[12];
    const int*   flag_num  = (const int*)d_in[13];

    float* out = (float*)d_out;

    dim3 block(256);
    dim3 grid(HD / TX, HD / TY);   // 32 x 64 blocks

    fused_kernel<<<grid, block, 0, stream>>>(batch, ref_speed, x_tt, x_t,
                                             conv_v, conv_g, conv_b,
                                             bsize, flag, flag_num, out);
    scatter_kernel<<<1, 256, 0, stream>>>(ref_sol, loc_x, loc_y, bsize, id, flag_num, out);
}